// Round 10
// baseline (1879.410 us; speedup 1.0000x reference)
//
#include <hip/hip_runtime.h>

#define T_TOK 8192   // B*S tokens
#define HDIM  2048
#define IDIM  8192
#define KKEEP 4096

typedef _Float16 f16x8 __attribute__((ext_vector_type(8)));
typedef float    f32x4 __attribute__((ext_vector_type(4)));

#define AS1 __attribute__((address_space(1)))
#define AS3 __attribute__((address_space(3)))

#define BARR asm volatile("s_barrier" ::: "memory")

// LDS permutation for 64-B rows (BK=32): byte bits[4:5] ^= bits[7:8], bit[6] ^= bit[8].
// Involution (control bits 7,8 unmodified). Spreads 16 consecutive rows' same-column
// 16B-granules across all 8 bank-quads (2 lanes/quad = free).
__device__ __forceinline__ int swz(int b) {
    return b ^ ((b >> 3) & 0x30) ^ ((b >> 2) & 0x40);
}

// ---------------- cast kernels ----------------

__global__ void cast_split(const float4* __restrict__ in, ushort4* __restrict__ hi,
                           ushort4* __restrict__ lo2, long n4) {
    long stride = (long)gridDim.x * blockDim.x;
    for (long i = (long)blockIdx.x * blockDim.x + threadIdx.x; i < n4; i += stride) {
        float4 v = in[i];
        float vv[4] = {v.x, v.y, v.z, v.w};
        union { _Float16 f[4]; ushort4 u; } H, L;
        #pragma unroll
        for (int j = 0; j < 4; ++j) {
            _Float16 h = (_Float16)vv[j];
            H.f[j] = h;
            L.f[j] = (_Float16)((vv[j] - (float)h) * 2048.0f);
        }
        hi[i] = H.u;
        lo2[i] = L.u;
    }
}

__global__ void cast_f16(const float4* __restrict__ in, ushort4* __restrict__ o, long n4) {
    long stride = (long)gridDim.x * blockDim.x;
    for (long i = (long)blockIdx.x * blockDim.x + threadIdx.x; i < n4; i += stride) {
        float4 v = in[i];
        float vv[4] = {v.x, v.y, v.z, v.w};
        union { _Float16 f[4]; ushort4 u; } H;
        #pragma unroll
        for (int j = 0; j < 4; ++j) H.f[j] = (_Float16)vv[j];
        o[i] = H.u;
    }
}

// ------- 256x256 GEMM, BK=32, 4-deep LDS pipeline (stage lead = 3 K-tiles) -------
// MODE 0: DOWN — Cf = A0@B0^T (f32)
// MODE 1: UP   — in-place GP[idx] = (f16)((float)GP[idx] * acc)
// MODE 2: GATE — acc = A0@B0^T + A1@B1^T; acc *= 2^-11; acc += A2@B2^T; Cf f32

// stage one full K-tile (32 KB: A 16KB + B 16KB) into buffer buf_
#define STAGE4(pA_, pB_, kt_, buf_) do { \
    char* db_ = Lc + (buf_)*32768 + wave*1024; \
    __builtin_amdgcn_global_load_lds((const AS1 void*)((pA_) + aBase + (kt_) + off0), \
                                     (AS3 void*)(db_),         16, 0, 0); \
    __builtin_amdgcn_global_load_lds((const AS1 void*)((pA_) + aBase + (kt_) + off1), \
                                     (AS3 void*)(db_ +  8192), 16, 0, 0); \
    __builtin_amdgcn_global_load_lds((const AS1 void*)((pB_) + bBase + (kt_) + off2), \
                                     (AS3 void*)(db_ + 16384), 16, 0, 0); \
    __builtin_amdgcn_global_load_lds((const AS1 void*)((pB_) + bBase + (kt_) + off3), \
                                     (AS3 void*)(db_ + 24576), 16, 0, 0); \
  } while (0)

template <int MODE>
__global__ __launch_bounds__(512, 2) void gemm4(
    const _Float16* __restrict__ A0, const _Float16* __restrict__ B0,
    const _Float16* __restrict__ A1, const _Float16* __restrict__ B1,
    const _Float16* __restrict__ A2, const _Float16* __restrict__ B2,
    int N, int Kp, float* __restrict__ Cf, _Float16* __restrict__ GP)
{
    __shared__ __align__(128) char Lc[131072];   // 4 bufs x 32 KB (A 16K | B 16K)
    const int tid  = threadIdx.x;
    const int lane = tid & 63;
    const int wave = tid >> 6;
    const int wr = wave >> 2, wc = wave & 3;     // 2 x 4 waves; wave tile 128x64

    // XCD-bijective swizzle of flattened block id
    const int gx = gridDim.x, gy = gridDim.y;
    const int nwg = gx * gy;
    const int orig = blockIdx.y * gx + blockIdx.x;
    const int q = nwg >> 3, r = nwg & 7, xcd = orig & 7, lid = orig >> 3;
    const int wg = (xcd < r ? xcd * (q + 1) : r * (q + 1) + (xcd - r) * q) + lid;
    const int bm = wg / gy, bn = wg % gy;

    // staging map: linear LDS dest (tid*16) <- inverse-swizzled global source.
    // g=0,1 cover A rows [0,256); g=2,3 cover B rows [0,256).
    int off0, off1, off2, off3;
    {
        int o[4];
        #pragma unroll
        for (int g = 0; g < 4; ++g) {
            int p = g * 8192 + tid * 16;
            int l = swz(p);
            int row = (l >> 6) & 255;
            int col = (l & 63) >> 1;
            o[g] = row * Kp + col;
        }
        off0 = o[0]; off1 = o[1]; off2 = o[2]; off3 = o[3];
    }
    const size_t aBase = (size_t)bm * 256 * Kp;
    const size_t bBase = (size_t)bn * 256 * Kp;

    // swizzled ds_read bases; m/n strides of 1024 B are swz-invariant (bits >= 10)
    const int l15 = lane & 15, lhi = lane >> 4;
    const int pa = swz((wr * 128 + l15) * 64 + lhi * 16);
    const int pb = swz(16384 + (wc * 64 + l15) * 64 + lhi * 16);

    const int tpp = Kp >> 5;                      // K-tiles per pass (BK=32)
    const int NT  = (MODE == 2 ? 3 : 1) * tpp;

    f32x4 acc[8][4] = {};

    // prologue: stage tiles 0,1,2 (12 loads in flight)
    STAGE4(A0, B0, 0,  0);
    STAGE4(A0, B0, 32, 1);
    STAGE4(A0, B0, 64, 2);

    for (int t = 0; t < NT; ++t) {
        // gate: tile t's 4 loads retired (FIFO); keep younger 8 in flight
        const int rem = NT - t;
        if (rem >= 3)      asm volatile("s_waitcnt vmcnt(8)" ::: "memory");
        else if (rem == 2) asm volatile("s_waitcnt vmcnt(4)" ::: "memory");
        else               asm volatile("s_waitcnt vmcnt(0)" ::: "memory");
        BARR;

        if (MODE == 2 && t == 2 * tpp) {
            #pragma unroll
            for (int m = 0; m < 8; ++m)
                #pragma unroll
                for (int n = 0; n < 4; ++n)
                    acc[m][n] *= (1.0f / 2048.0f);
        }

        // 12 ds_reads for this tile
        const char* bp = Lc + (t & 3) * 32768;
        f16x8 af[8], bfv[4];
        #pragma unroll
        for (int m = 0; m < 8; ++m) af[m]  = *(const f16x8*)(bp + pa + m * 1024);
        #pragma unroll
        for (int n = 0; n < 4; ++n) bfv[n] = *(const f16x8*)(bp + pb + n * 1024);

        // stage tile t+3 into buffer (t+3)&3
        const int ts = t + 3;
        if (ts < NT) {
            const _Float16 *pA1 = A0, *pB1 = B0;
            int tl = ts;
            if (MODE == 2) {
                int ps = 0;
                if (tl >= tpp) { ps = 1; tl -= tpp; }
                if (tl >= tpp) { ps = 2; tl -= tpp; }
                pA1 = ps == 0 ? A0 : (ps == 1 ? A1 : A2);
                pB1 = ps == 0 ? B0 : (ps == 1 ? B1 : B2);
            }
            const int kt1 = tl << 5;
            STAGE4(pA1, pB1, kt1, ts & 3);
        }

        // drain own reads, pin, MFMA (MFMAs may sink into next tile's window)
        asm volatile("s_waitcnt lgkmcnt(0)" ::: "memory");
        __builtin_amdgcn_sched_barrier(0);
        __builtin_amdgcn_s_setprio(1);
        #pragma unroll
        for (int m = 0; m < 8; ++m)
            #pragma unroll
            for (int n = 0; n < 4; ++n)
                acc[m][n] = __builtin_amdgcn_mfma_f32_16x16x32_f16(af[m], bfv[n], acc[m][n], 0, 0, 0);
        __builtin_amdgcn_s_setprio(0);
    }

    // epilogue; C/D layout: col = lane&15, row = (lane>>4)*4 + reg
    const int r0 = bm * 256 + wr * 128 + (lane >> 4) * 4;
    const int c0 = bn * 256 + wc * 64 + (lane & 15);
    #pragma unroll
    for (int m = 0; m < 8; ++m) {
        #pragma unroll
        for (int n = 0; n < 4; ++n) {
            #pragma unroll
            for (int rr = 0; rr < 4; ++rr) {
                const int row = r0 + m * 16 + rr;
                const int col = c0 + n * 16;
                const size_t idx = (size_t)row * N + col;
                if (MODE == 1) {
                    float g = (float)GP[idx];
                    GP[idx] = (_Float16)(g * acc[m][n][rr]);
                } else {
                    Cf[idx] = acc[m][n][rr];
                }
            }
        }
    }
}

// ---------------- exact K-th largest |gate| per token + fused mask write ----------------

__global__ __launch_bounds__(256) void topk_mask(const float* __restrict__ gate,
                                                 _Float16* __restrict__ gm) {
    __shared__ unsigned keys[IDIM];
    __shared__ unsigned hist[256];
    __shared__ unsigned sA[256], sB[256];
    __shared__ unsigned selBin, selAbove;

    const int tid = threadIdx.x;
    const int t = blockIdx.x;
    const float* row = gate + (size_t)t * IDIM;

    for (int j = tid; j < IDIM; j += 256)
        keys[j] = __float_as_uint(fabsf(row[j]));
    __syncthreads();

    unsigned prefix = 0;
    int Krem = KKEEP;
    for (int pass = 0; pass < 4; ++pass) {
        const int shift = 24 - 8 * pass;
        hist[tid] = 0;
        __syncthreads();
        for (int j = tid; j < IDIM; j += 256) {
            unsigned k = keys[j];
            bool ok = (pass == 0) || (((k ^ prefix) >> (shift + 8)) == 0u);
            if (ok) atomicAdd(&hist[(k >> shift) & 255u], 1u);
        }
        __syncthreads();
        sA[tid] = hist[tid];
        __syncthreads();
        unsigned* src = sA; unsigned* dst = sB;
        for (int off = 1; off < 256; off <<= 1) {
            unsigned v = src[tid] + ((tid + off < 256) ? src[tid + off] : 0u);
            dst[tid] = v;
            __syncthreads();
            unsigned* tmp = src; src = dst; dst = tmp;
        }
        unsigned S  = src[tid];
        unsigned Sn = (tid < 255) ? src[tid + 1] : 0u;
        if ((int)S >= Krem && (int)Sn < Krem) { selBin = (unsigned)tid; selAbove = Sn; }
        __syncthreads();
        prefix |= (selBin << shift);
        Krem -= (int)selAbove;
        __syncthreads();
    }
    const float kthv = __uint_as_float(prefix);
    _Float16* g16 = gm + (size_t)t * IDIM;
    for (int j = tid; j < IDIM; j += 256) {
        float g = row[j];
        g16[j] = (fabsf(g) >= kthv) ? (_Float16)g : (_Float16)0.0f;
    }
}

// ---------------- host ----------------

extern "C" void kernel_launch(void* const* d_in, const int* in_sizes, int n_in,
                              void* d_out, int out_size, void* d_ws, size_t ws_size,
                              hipStream_t stream) {
    const float* x  = (const float*)d_in[0];   // [T,H]
    const float* Wg = (const float*)d_in[1];   // [I,H]
    const float* Wu = (const float*)d_in[2];   // [I,H]
    const float* Wd = (const float*)d_in[3];   // [H,I]

    const size_t NE   = (size_t)T_TOK * HDIM;
    const size_t szH2 = NE * 2;                          // 33.55 MB

    char* ws = (char*)d_ws;
    _Float16* xh    = (_Float16*)ws;
    _Float16* Wb    = (_Float16*)(ws + szH2);            // Wgh, later Wu16
    _Float16* Wc    = (_Float16*)(ws + 2 * szH2);        // Wgl2, later Wd16
    _Float16* gmask = (_Float16*)(ws + 3 * szH2);        // masked gate f16 -> P (in place)
    _Float16* xl2   = gmask + (size_t)6144 * IDIM;       // parked; consumed before overwritten
    float* gate = (float*)d_out;                         // 2048-token f32 gate chunk

    const long n4 = (long)(NE / 4);
    cast_split<<<1024, 256, 0, stream>>>((const float4*)x,  (ushort4*)xh, (ushort4*)xl2, n4);
    cast_split<<<1024, 256, 0, stream>>>((const float4*)Wg, (ushort4*)Wb, (ushort4*)Wc,  n4);

    // gate phase: fused 3-pass split-f16 GEMM:
    // acc = xl2@Wgh + xh@Wgl2; acc *= 2^-11; acc += xh@Wgh
    for (int c0 = 0; c0 < T_TOK; c0 += 2048) {
        const _Float16* xh_c  = xh  + (size_t)c0 * HDIM;
        const _Float16* xl2_c = xl2 + (size_t)c0 * HDIM;
        gemm4<2><<<dim3(2048 / 256, IDIM / 256), 512, 0, stream>>>(
            xl2_c, Wb, xh_c, Wc, xh_c, Wb, IDIM, HDIM, gate, nullptr);
        topk_mask<<<2048, 256, 0, stream>>>(gate, gmask + (size_t)c0 * IDIM);
    }

    // re-cast weight slots for UP / DOWN
    cast_f16<<<1024, 256, 0, stream>>>((const float4*)Wu, (ushort4*)Wb, n4);
    cast_f16<<<1024, 256, 0, stream>>>((const float4*)Wd, (ushort4*)Wc, n4);

    // UP: in-place P = gmask * (xh @ Wu^T)
    gemm4<1><<<dim3(T_TOK / 256, IDIM / 256), 512, 0, stream>>>(
        xh, Wb, nullptr, nullptr, nullptr, nullptr, IDIM, HDIM, nullptr, gmask);

    // DOWN: out = P @ Wd^T
    gemm4<0><<<dim3(T_TOK / 256, HDIM / 256), 512, 0, stream>>>(
        (const _Float16*)gmask, Wc, nullptr, nullptr, nullptr, nullptr,
        HDIM, IDIM, (float*)d_out, nullptr);
}